// Round 11
// baseline (407.728 us; speedup 1.0000x reference)
//
#include <hip/hip_runtime.h>
#include <hip/hip_bf16.h>
#include <math.h>

typedef __bf16 bf16x8 __attribute__((ext_vector_type(8)));
typedef float  f32x4  __attribute__((ext_vector_type(4)));

__device__ __forceinline__ unsigned short f2b(float f) {
    union { float f; unsigned u; } v; v.f = f;
    unsigned r = v.u + 0x7fffu + ((v.u >> 16) & 1u);   // RNE
    return (unsigned short)(r >> 16);
}
__device__ __forceinline__ float b2f_lo(unsigned u) {
    union { unsigned u; float f; } v; v.u = u << 16; return v.f;
}
__device__ __forceinline__ float b2f_hi(unsigned u) {
    union { unsigned u; float f; } v; v.u = u & 0xffff0000u; return v.f;
}

// ================= CSR build: two-level counting sort (LDS atomics only) ====
// csr PADDED: each node's list 16-aligned, length rounded to x16, pads = -1.
// nchk[i] = padded length / 4.

#define NB_SC 128
#define BUKPAD 8192   // per-bucket pad budget; provably >= 15 + 512*15, 16-divisible

// hist + fused weight-prep (bf16 transpose) + hist zero-pad
__global__ __launch_bounds__(256) void k_hist(const int* __restrict__ dstA,
                                              int* __restrict__ hist_g,
                                              int E, int nbuk, int chunk,
                                              const float* __restrict__ W1,
                                              const float* __restrict__ W2,
                                              __bf16* __restrict__ W1t,
                                              __bf16* __restrict__ W2t,
                                              int M, int Mpad) {
    __shared__ int h[256];
    const int t = threadIdx.x, b = blockIdx.x;
    h[t] = 0;
    __syncthreads();
    const int e0 = b * chunk, e1 = min(E, e0 + chunk);
    for (int e = e0 + t; e < e1; e += 256) atomicAdd(&h[dstA[e] >> 9], 1);
    const int gid = b * 256 + t;
    for (int idx = gid; idx < 128 * 128; idx += NB_SC * 256) {
        int k = idx >> 7, c = idx & 127;
        W1t[c * 128 + k] = (__bf16)W1[idx];
    }
    for (int idx = gid; idx < 64 * 128; idx += NB_SC * 256) {
        int c = idx >> 7, k = idx & 127;
        W2t[idx] = (c < 40) ? (__bf16)W2[k * 40 + c] : (__bf16)0.f;
    }
    for (int idx = M + gid; idx < Mpad; idx += NB_SC * 256) hist_g[idx] = 0;
    __syncthreads();
    if (t < nbuk) hist_g[t * NB_SC + b] = h[t];
}

__global__ __launch_bounds__(1024) void k_scan_hist(int* __restrict__ hist, int per) {
    __shared__ int ts[1024];
    const int t = threadIdx.x;
    const int base = t * per;
    int4 v[16];
    const int nv = per >> 2;
    int sum = 0;
    #pragma unroll 4
    for (int j = 0; j < nv; ++j) {
        v[j] = *(const int4*)(hist + base + j * 4);
        sum += v[j].x + v[j].y + v[j].z + v[j].w;
    }
    ts[t] = sum;
    __syncthreads();
    for (int o = 1; o < 1024; o <<= 1) {
        int a = (t >= o) ? ts[t - o] : 0;
        __syncthreads();
        ts[t] += a;
        __syncthreads();
    }
    int run = (t == 0) ? 0 : ts[t - 1];
    #pragma unroll 4
    for (int j = 0; j < nv; ++j) {
        int a;
        a = v[j].x; v[j].x = run; run += a;
        a = v[j].y; v[j].y = run; run += a;
        a = v[j].z; v[j].z = run; run += a;
        a = v[j].w; v[j].w = run; run += a;
        *(int4*)(hist + base + j * 4) = v[j];
    }
}

__global__ __launch_bounds__(256) void k_scatter(const int* __restrict__ srcA,
                                                 const int* __restrict__ dstA,
                                                 const int* __restrict__ base,
                                                 unsigned* __restrict__ part,
                                                 int E, int nbuk, int chunk) {
    __shared__ int cur[256];
    const int t = threadIdx.x, b = blockIdx.x;
    if (t < nbuk) cur[t] = base[t * NB_SC + b];
    __syncthreads();
    const int e0 = b * chunk, e1 = min(E, e0 + chunk);
    for (int e = e0 + t; e < e1; e += 256) {
        int d = dstA[e];
        int s = srcA[e];
        int buk = d >> 9;
        int p = atomicAdd(&cur[buk], 1);
        part[p] = ((unsigned)s << 9) | (unsigned)(d & 511);
    }
}

__global__ __launch_bounds__(512) void k_lcsr(const unsigned* __restrict__ part,
                                              const int* __restrict__ base,
                                              int* __restrict__ csr,
                                              int* __restrict__ offs,
                                              int* __restrict__ nchk,
                                              float* __restrict__ isq,
                                              int E, int N, int nbuk) {
    __shared__ int deg[512];
    __shared__ int sc[512];
    __shared__ int cur[512];
    const int t = threadIdx.x, buk = blockIdx.x;
    const int n0 = buk << 9;
    const int nn = min(512, N - n0);
    const int e0r = base[buk * NB_SC];
    const int e1r = (buk + 1 < nbuk) ? base[(buk + 1) * NB_SC] : E;
    deg[t] = 0;
    __syncthreads();
    for (int e = e0r + t; e < e1r; e += 512) atomicAdd(&deg[part[e] & 511], 1);
    __syncthreads();
    const int dg = deg[t];
    const int pdeg = (dg + 15) & ~15;         // x16 pad (agg1s reads 16 slots/iter)
    sc[t] = pdeg;
    __syncthreads();
    for (int o = 1; o < 512; o <<= 1) {
        int a = (t >= o) ? sc[t - o] : 0;
        __syncthreads();
        sc[t] += a;
        __syncthreads();
    }
    const int excl = (t == 0) ? 0 : sc[t - 1];
    const int pbase = ((e0r + 15) & ~15) + buk * BUKPAD;
    const int start = pbase + excl;
    cur[t] = start;
    if (t < nn) {
        offs[n0 + t] = start;
        nchk[n0 + t] = pdeg >> 2;
        isq[n0 + t]  = rsqrtf((float)(dg + 1));
    }
    for (int j = dg; j < pdeg; ++j) csr[start + j] = -1;   // <=15 pads per node
    __syncthreads();
    for (int e = e0r + t; e < e1r; e += 512) {
        unsigned w = part[e];
        int dl = (int)(w & 511u);
        int p = atomicAdd(&cur[dl], 1);
        csr[p] = (int)(w >> 9);
    }
}

// ------- GEMM1 (MFMA): Hs1 = bf16((x @ W1) * isq[row]), SLICED 16-ch output ----
// Hs1 layout: slice s (=col/16): Hs1[s*(N+8)*16 + row*16 + col%16]; row N zeroed.

__global__ __launch_bounds__(256) void k_gemm1(const float* __restrict__ x,
                                               const __bf16* __restrict__ W1t,
                                               const float* __restrict__ isq,
                                               unsigned short* __restrict__ out, int n) {
    const size_t nrow = (size_t)n + 8;
    if (blockIdx.x == 0 && threadIdx.x < 128) {   // zero sentinel rows (8 slices x 16ch)
        int sl = threadIdx.x >> 4, c = threadIdx.x & 15;
        out[sl * nrow * 16 + (size_t)n * 16 + c] = 0;
    }
    const int lane = threadIdx.x & 63;
    const int wid  = blockIdx.x * 4 + (threadIdx.x >> 6);
    const int r0 = wid * 16;
    if (r0 >= n) return;
    const int mr = lane & 15;
    const int kg = lane >> 4;

    bf16x8 af[4];
    const float* xrow = x + (size_t)(r0 + mr) * 128 + kg * 8;
    #pragma unroll
    for (int s = 0; s < 4; ++s) {
        f32x4 u0 = *(const f32x4*)(xrow + s * 32);
        f32x4 u1 = *(const f32x4*)(xrow + s * 32 + 4);
        bf16x8 a;
        a[0] = (__bf16)u0[0]; a[1] = (__bf16)u0[1]; a[2] = (__bf16)u0[2]; a[3] = (__bf16)u0[3];
        a[4] = (__bf16)u1[0]; a[5] = (__bf16)u1[1]; a[6] = (__bf16)u1[2]; a[7] = (__bf16)u1[3];
        af[s] = a;
    }
    float sc[4];
    #pragma unroll
    for (int r = 0; r < 4; ++r) sc[r] = isq[r0 + kg * 4 + r];

    #pragma unroll
    for (int nt = 0; nt < 8; ++nt) {
        const __bf16* wp = W1t + (size_t)(nt * 16 + mr) * 128 + kg * 8;
        f32x4 acc = {0.f, 0.f, 0.f, 0.f};
        #pragma unroll
        for (int s = 0; s < 4; ++s) {
            bf16x8 bfr = *(const bf16x8*)(wp + s * 32);
            acc = __builtin_amdgcn_mfma_f32_16x16x32_bf16(af[s], bfr, acc, 0, 0, 0);
        }
        #pragma unroll
        for (int r = 0; r < 4; ++r) {
            int row = r0 + kg * 4 + r;
            out[nt * nrow * 16 + (size_t)row * 16 + mr] = f2b(acc[r] * sc[r]);
        }
    }
}

// ------- agg1 SLICED+PINNED: slice = blockIdx%8 -> one XCD owns one 3.2MB slice ----
// wave per node-slice; 4 lanes x 8B per edge; 16 edges in flight per iter.
// SELF LOOP ONLY IN g==0 LANES (reduce sums over the 16 edge groups!).
// H1 written UNsliced (256B rows) for gemm2.

__global__ __launch_bounds__(256) void k_agg1s(const unsigned short* __restrict__ Hsl,
                                               const int* __restrict__ csr,
                                               const int* __restrict__ offs,
                                               const int* __restrict__ nchk,
                                               const float* __restrict__ isq,
                                               const float* __restrict__ b1,
                                               unsigned short* __restrict__ out, int n) {
    const int slice = blockIdx.x & 7;
    const int node  = (blockIdx.x >> 3) * 4 + (threadIdx.x >> 6);
    if (node >= n) return;
    const int lane = threadIdx.x & 63;
    const int g = lane >> 2;                  // edge slot 0..15
    const int q = lane & 3;                   // 8B piece (4 ch)
    const size_t nrow = (size_t)n + 8;
    const unsigned short* T = Hsl + (size_t)slice * nrow * 16;

    const int e0 = offs[node];
    const int nit = nchk[node] >> 2;          // windows of 16 (pdeg x16)

    float a0 = 0.f, a1 = 0.f, a2 = 0.f, a3 = 0.f;
    if (g == 0) {   // self loop — ONCE per node (g==0 group only)
        int2 w = *(const int2*)(T + (size_t)node * 16 + q * 4);
        a0 = b2f_lo((unsigned)w.x); a1 = b2f_hi((unsigned)w.x);
        a2 = b2f_lo((unsigned)w.y); a3 = b2f_hi((unsigned)w.y);
    }

    for (int it = 0; it < nit; ++it) {
        int cur = csr[e0 + it * 16 + g];
        unsigned srow = min((unsigned)cur, (unsigned)n);   // -1 -> zero row n
        int2 w = *(const int2*)(T + (size_t)srow * 16 + q * 4);
        a0 += b2f_lo((unsigned)w.x); a1 += b2f_hi((unsigned)w.x);
        a2 += b2f_lo((unsigned)w.y); a3 += b2f_hi((unsigned)w.y);
    }
    // reduce across the 16 edge slots (lanes stride 4)
    a0 += __shfl_xor(a0, 4, 64);  a1 += __shfl_xor(a1, 4, 64);
    a2 += __shfl_xor(a2, 4, 64);  a3 += __shfl_xor(a3, 4, 64);
    a0 += __shfl_xor(a0, 8, 64);  a1 += __shfl_xor(a1, 8, 64);
    a2 += __shfl_xor(a2, 8, 64);  a3 += __shfl_xor(a3, 8, 64);
    a0 += __shfl_xor(a0, 16, 64); a1 += __shfl_xor(a1, 16, 64);
    a2 += __shfl_xor(a2, 16, 64); a3 += __shfl_xor(a3, 16, 64);
    a0 += __shfl_xor(a0, 32, 64); a1 += __shfl_xor(a1, 32, 64);
    a2 += __shfl_xor(a2, 32, 64); a3 += __shfl_xor(a3, 32, 64);

    if (g == 0) {   // lanes 0..3 write 8B each -> 32B of the 256B H1 row
        const float s = isq[node];
        f32x4 bb = *(const f32x4*)(b1 + slice * 16 + q * 4);
        unsigned short o0 = f2b(fmaxf(fmaf(a0, s, bb[0]), 0.f));
        unsigned short o1 = f2b(fmaxf(fmaf(a1, s, bb[1]), 0.f));
        unsigned short o2 = f2b(fmaxf(fmaf(a2, s, bb[2]), 0.f));
        unsigned short o3 = f2b(fmaxf(fmaf(a3, s, bb[3]), 0.f));
        int2 r;
        r.x = (int)((unsigned)o0 | ((unsigned)o1 << 16));
        r.y = (int)((unsigned)o2 | ((unsigned)o3 << 16));
        *(int2*)(out + (size_t)node * 128 + slice * 16 + q * 4) = r;
    }
}

// ------- GEMM2 (MFMA): Hs2 = bf16((H1 @ W2pad64) * isq[row]), 64-wide out ----

__global__ __launch_bounds__(256) void k_gemm2(const __bf16* __restrict__ h,
                                               const __bf16* __restrict__ W2t,
                                               const float* __restrict__ isq,
                                               unsigned short* __restrict__ out, int n) {
    if (blockIdx.x == 0 && threadIdx.x < 8) {
        int4 z = {0, 0, 0, 0};
        *(int4*)(out + (size_t)n * 64 + threadIdx.x * 8) = z;
    }
    const int lane = threadIdx.x & 63;
    const int wid  = blockIdx.x * 4 + (threadIdx.x >> 6);
    const int r0 = wid * 16;
    if (r0 >= n) return;
    const int mr = lane & 15;
    const int kg = lane >> 4;

    bf16x8 af[4];
    const __bf16* hrow = h + (size_t)(r0 + mr) * 128 + kg * 8;
    #pragma unroll
    for (int s = 0; s < 4; ++s) af[s] = *(const bf16x8*)(hrow + s * 32);
    float sc[4];
    #pragma unroll
    for (int r = 0; r < 4; ++r) sc[r] = isq[r0 + kg * 4 + r];

    #pragma unroll
    for (int nt = 0; nt < 4; ++nt) {
        const __bf16* wp = W2t + (size_t)(nt * 16 + mr) * 128 + kg * 8;
        f32x4 acc = {0.f, 0.f, 0.f, 0.f};
        #pragma unroll
        for (int s = 0; s < 4; ++s) {
            bf16x8 bfr = *(const bf16x8*)(wp + s * 32);
            acc = __builtin_amdgcn_mfma_f32_16x16x32_bf16(af[s], bfr, acc, 0, 0, 0);
        }
        int col = nt * 16 + mr;
        #pragma unroll
        for (int r = 0; r < 4; ++r) {
            int row = r0 + kg * 4 + r;
            out[(size_t)row * 64 + col] = f2b(acc[r] * sc[r]);
        }
    }
}

// ------- agg2: wave/node, 8 lanes x 16B per edge row, 8 edges/iter -------

__global__ __launch_bounds__(256) void k_agg2(const unsigned short* __restrict__ Hs,
                                              const int* __restrict__ csr,
                                              const int* __restrict__ offs,
                                              const int* __restrict__ nchk,
                                              const float* __restrict__ isq,
                                              const float* __restrict__ b2,
                                              float* __restrict__ out, int n) {
    int wid = (int)((blockIdx.x * (size_t)blockDim.x + threadIdx.x) >> 6);
    if (wid >= n) return;
    const int lane = threadIdx.x & 63;
    const int g = lane >> 3, p = lane & 7;
    const int d = wid;
    const int e0 = offs[d];
    const int nc8 = nchk[d] >> 1;             // chunks of 8 (pdeg x16 -> exact)

    float acc[8];
    #pragma unroll
    for (int j = 0; j < 8; ++j) acc[j] = 0.f;
    if (g == 0) {   // self — once (g==0 group only)
        int4 w = *(const int4*)(Hs + (size_t)d * 64 + p * 8);
        acc[0] = b2f_lo((unsigned)w.x); acc[1] = b2f_hi((unsigned)w.x);
        acc[2] = b2f_lo((unsigned)w.y); acc[3] = b2f_hi((unsigned)w.y);
        acc[4] = b2f_lo((unsigned)w.z); acc[5] = b2f_hi((unsigned)w.z);
        acc[6] = b2f_lo((unsigned)w.w); acc[7] = b2f_hi((unsigned)w.w);
    }
    #pragma unroll 4
    for (int c = 0; c < nc8; ++c) {
        int cur = csr[e0 + 8 * c + g];
        unsigned srow = min((unsigned)cur, (unsigned)n);
        int4 w = *(const int4*)(Hs + (size_t)srow * 64 + p * 8);
        acc[0] += b2f_lo((unsigned)w.x); acc[1] += b2f_hi((unsigned)w.x);
        acc[2] += b2f_lo((unsigned)w.y); acc[3] += b2f_hi((unsigned)w.y);
        acc[4] += b2f_lo((unsigned)w.z); acc[5] += b2f_hi((unsigned)w.z);
        acc[6] += b2f_lo((unsigned)w.w); acc[7] += b2f_hi((unsigned)w.w);
    }
    #pragma unroll
    for (int j = 0; j < 8; ++j) {
        acc[j] += __shfl_xor(acc[j], 8, 64);
        acc[j] += __shfl_xor(acc[j], 16, 64);
        acc[j] += __shfl_xor(acc[j], 32, 64);
    }
    if (g == 0) {
        const float s = isq[d];
        const bool real = p < 5;
        float v[8];
        if (real) {
            f32x4 b0 = *(const f32x4*)(b2 + p * 8);
            f32x4 b1v = *(const f32x4*)(b2 + p * 8 + 4);
            v[0] = fmaf(acc[0], s, b0[0]);  v[1] = fmaf(acc[1], s, b0[1]);
            v[2] = fmaf(acc[2], s, b0[2]);  v[3] = fmaf(acc[3], s, b0[3]);
            v[4] = fmaf(acc[4], s, b1v[0]); v[5] = fmaf(acc[5], s, b1v[1]);
            v[6] = fmaf(acc[6], s, b1v[2]); v[7] = fmaf(acc[7], s, b1v[3]);
        } else {
            #pragma unroll
            for (int j = 0; j < 8; ++j) v[j] = -INFINITY;
        }
        float lm = v[0];
        #pragma unroll
        for (int j = 1; j < 8; ++j) lm = fmaxf(lm, v[j]);
        lm = fmaxf(lm, __shfl_xor(lm, 1, 64));
        lm = fmaxf(lm, __shfl_xor(lm, 2, 64));
        lm = fmaxf(lm, __shfl_xor(lm, 4, 64));
        float es = 0.f;
        if (real) {
            #pragma unroll
            for (int j = 0; j < 8; ++j) es += expf(v[j] - lm);
        }
        es += __shfl_xor(es, 1, 64);
        es += __shfl_xor(es, 2, 64);
        es += __shfl_xor(es, 4, 64);
        float lse = lm + logf(es);
        if (real) {
            f32x4 r0, r1;
            r0[0] = v[0] - lse; r0[1] = v[1] - lse; r0[2] = v[2] - lse; r0[3] = v[3] - lse;
            r1[0] = v[4] - lse; r1[1] = v[5] - lse; r1[2] = v[6] - lse; r1[3] = v[7] - lse;
            float* op = out + (size_t)d * 40 + p * 8;
            *(f32x4*)op = r0;
            *(f32x4*)(op + 4) = r1;
        }
    }
}

// ---------------- launch ----------------

extern "C" void kernel_launch(void* const* d_in, const int* in_sizes, int n_in,
                              void* d_out, int out_size, void* d_ws, size_t ws_size,
                              hipStream_t stream) {
    const float* x  = (const float*)d_in[0];
    const int*   ei = (const int*)d_in[1];
    const float* W1 = (const float*)d_in[2];
    const float* b1 = (const float*)d_in[3];
    const float* W2 = (const float*)d_in[4];
    const float* b2 = (const float*)d_in[5];
    float* out = (float*)d_out;

    const int N = in_sizes[0] / 128;
    const int E = in_sizes[1] / 2;
    const int* srcA = ei;
    const int* dstA = ei + E;
    const int nbuk = (N + 511) >> 9;
    const int chunk = (E + NB_SC - 1) / NB_SC;
    const int M = nbuk * NB_SC;
    int per = (M + 1023) >> 10;
    per = (per + 3) & ~3;
    const int Mpad = per * 1024;
    const int csrCap = E + nbuk * BUKPAD + 64;

    char* ws = (char*)d_ws;
    size_t off = 0;
    auto alloc = [&](size_t bytes) -> void* {
        void* p = ws + off;
        off += (bytes + 255) & ~(size_t)255;
        return p;
    };
    int*      hist = (int*)alloc((size_t)Mpad * 4);
    unsigned* part = (unsigned*)alloc((size_t)E * 4);
    int*      offs = (int*)alloc((size_t)N * 4);
    int*      nchk = (int*)alloc((size_t)N * 4);
    float*    isq  = (float*)alloc((size_t)N * 4);
    int*      csr  = (int*)alloc((size_t)csrCap * 4);
    __bf16*   W1t  = (__bf16*)alloc(128 * 128 * 2);
    __bf16*   W2t  = (__bf16*)alloc(64 * 128 * 2);
    unsigned short* Hs1 = (unsigned short*)alloc((size_t)(N + 8) * 128 * 2);  // 8 slices x (N+8) x 16
    unsigned short* H1  = (unsigned short*)alloc((size_t)N * 128 * 2);
    unsigned short* Hs2 = (unsigned short*)alloc((size_t)(N + 8) * 64 * 2);

    k_hist<<<NB_SC, 256, 0, stream>>>(dstA, hist, E, nbuk, chunk,
                                      W1, W2, W1t, W2t, M, Mpad);
    k_scan_hist<<<1, 1024, 0, stream>>>(hist, per);
    k_scatter<<<NB_SC, 256, 0, stream>>>(srcA, dstA, hist, part, E, nbuk, chunk);
    k_lcsr<<<nbuk, 512, 0, stream>>>(part, hist, csr, offs, nchk, isq, E, N, nbuk);

    const int nwav = (N + 15) / 16;
    k_gemm1<<<(nwav + 3) / 4, 256, 0, stream>>>(x, W1t, isq, Hs1, N);
    const int nnb = (N + 3) / 4;               // 4 nodes per block, x8 slices
    k_agg1s<<<nnb * 8, 256, 0, stream>>>(Hs1, csr, offs, nchk, isq, b1, H1, N);
    k_gemm2<<<(nwav + 3) / 4, 256, 0, stream>>>((const __bf16*)H1, W2t, isq, Hs2, N);
    k_agg2<<<(N + 3) / 4, 256, 0, stream>>>(Hs2, csr, offs, nchk, isq, b2, out, N);
}

// Round 12
// 243.788 us; speedup vs baseline: 1.6725x; 1.6725x over previous
//
#include <hip/hip_runtime.h>
#include <hip/hip_bf16.h>
#include <math.h>

typedef __bf16 bf16x8 __attribute__((ext_vector_type(8)));
typedef float  f32x4  __attribute__((ext_vector_type(4)));

__device__ __forceinline__ unsigned short f2b(float f) {
    union { float f; unsigned u; } v; v.f = f;
    unsigned r = v.u + 0x7fffu + ((v.u >> 16) & 1u);   // RNE
    return (unsigned short)(r >> 16);
}
__device__ __forceinline__ float b2f_lo(unsigned u) {
    union { unsigned u; float f; } v; v.u = u << 16; return v.f;
}
__device__ __forceinline__ float b2f_hi(unsigned u) {
    union { unsigned u; float f; } v; v.u = u & 0xffff0000u; return v.f;
}
// bijective XCD swizzle (m204): contiguous ranges of blocks -> one XCD
__device__ __forceinline__ int xcd_swizzle(int bid, int nwg) {
    int xcd = bid & 7, loc = bid >> 3;
    int q = nwg >> 3, r = nwg & 7;
    int base = (xcd < r) ? xcd * (q + 1) : r * (q + 1) + (xcd - r) * q;
    return base + loc;
}

// ================= CSR build: two-level counting sort (LDS atomics only) ====
// csr PADDED: each node's list 8-aligned, length rounded to x8, pads = -1.
// nchk[i] = padded length / 4.

#define NB_SC 128
#define BUKPAD 3584   // max padding per 512-node bucket (7 per node), 8-divisible

// hist + fused weight-prep (bf16 transpose) + hist zero-pad
__global__ __launch_bounds__(256) void k_hist(const int* __restrict__ dstA,
                                              int* __restrict__ hist_g,
                                              int E, int nbuk, int chunk,
                                              const float* __restrict__ W1,
                                              const float* __restrict__ W2,
                                              __bf16* __restrict__ W1t,
                                              __bf16* __restrict__ W2t,
                                              int M, int Mpad) {
    __shared__ int h[256];
    const int t = threadIdx.x, b = blockIdx.x;
    h[t] = 0;
    __syncthreads();
    const int e0 = b * chunk, e1 = min(E, e0 + chunk);
    for (int e = e0 + t; e < e1; e += 256) atomicAdd(&h[dstA[e] >> 9], 1);
    const int gid = b * 256 + t;
    for (int idx = gid; idx < 128 * 128; idx += NB_SC * 256) {
        int k = idx >> 7, c = idx & 127;
        W1t[c * 128 + k] = (__bf16)W1[idx];
    }
    for (int idx = gid; idx < 64 * 128; idx += NB_SC * 256) {
        int c = idx >> 7, k = idx & 127;
        W2t[idx] = (c < 40) ? (__bf16)W2[k * 40 + c] : (__bf16)0.f;
    }
    for (int idx = M + gid; idx < Mpad; idx += NB_SC * 256) hist_g[idx] = 0;
    __syncthreads();
    if (t < nbuk) hist_g[t * NB_SC + b] = h[t];
}

__global__ __launch_bounds__(1024) void k_scan_hist(int* __restrict__ hist, int per) {
    __shared__ int ts[1024];
    const int t = threadIdx.x;
    const int base = t * per;
    int4 v[16];
    const int nv = per >> 2;
    int sum = 0;
    #pragma unroll 4
    for (int j = 0; j < nv; ++j) {
        v[j] = *(const int4*)(hist + base + j * 4);
        sum += v[j].x + v[j].y + v[j].z + v[j].w;
    }
    ts[t] = sum;
    __syncthreads();
    for (int o = 1; o < 1024; o <<= 1) {
        int a = (t >= o) ? ts[t - o] : 0;
        __syncthreads();
        ts[t] += a;
        __syncthreads();
    }
    int run = (t == 0) ? 0 : ts[t - 1];
    #pragma unroll 4
    for (int j = 0; j < nv; ++j) {
        int a;
        a = v[j].x; v[j].x = run; run += a;
        a = v[j].y; v[j].y = run; run += a;
        a = v[j].z; v[j].z = run; run += a;
        a = v[j].w; v[j].w = run; run += a;
        *(int4*)(hist + base + j * 4) = v[j];
    }
}

__global__ __launch_bounds__(256) void k_scatter(const int* __restrict__ srcA,
                                                 const int* __restrict__ dstA,
                                                 const int* __restrict__ base,
                                                 unsigned* __restrict__ part,
                                                 int E, int nbuk, int chunk) {
    __shared__ int cur[256];
    const int t = threadIdx.x, b = blockIdx.x;
    if (t < nbuk) cur[t] = base[t * NB_SC + b];
    __syncthreads();
    const int e0 = b * chunk, e1 = min(E, e0 + chunk);
    for (int e = e0 + t; e < e1; e += 256) {
        int d = dstA[e];
        int s = srcA[e];
        int buk = d >> 9;
        int p = atomicAdd(&cur[buk], 1);
        part[p] = ((unsigned)s << 9) | (unsigned)(d & 511);
    }
}

// per-bucket: count -> padded scan -> fill padded csr (+ -1 pads); offs/nchk/isq
__global__ __launch_bounds__(512) void k_lcsr(const unsigned* __restrict__ part,
                                              const int* __restrict__ base,
                                              int* __restrict__ csr,
                                              int* __restrict__ offs,
                                              int* __restrict__ nchk,
                                              float* __restrict__ isq,
                                              int E, int N, int nbuk) {
    __shared__ int deg[512];
    __shared__ int sc[512];
    __shared__ int cur[512];
    const int t = threadIdx.x, buk = blockIdx.x;
    const int n0 = buk << 9;
    const int nn = min(512, N - n0);
    const int e0r = base[buk * NB_SC];
    const int e1r = (buk + 1 < nbuk) ? base[(buk + 1) * NB_SC] : E;
    deg[t] = 0;
    __syncthreads();
    for (int e = e0r + t; e < e1r; e += 512) atomicAdd(&deg[part[e] & 511], 1);
    __syncthreads();
    const int dg = deg[t];
    const int pdeg = (dg + 7) & ~7;
    sc[t] = pdeg;
    __syncthreads();
    for (int o = 1; o < 512; o <<= 1) {
        int a = (t >= o) ? sc[t - o] : 0;
        __syncthreads();
        sc[t] += a;
        __syncthreads();
    }
    const int excl = (t == 0) ? 0 : sc[t - 1];
    const int pbase = ((e0r + 7) & ~7) + buk * BUKPAD;
    const int start = pbase + excl;
    cur[t] = start;
    if (t < nn) {
        offs[n0 + t] = start;
        nchk[n0 + t] = pdeg >> 2;
        isq[n0 + t]  = rsqrtf((float)(dg + 1));
    }
    for (int j = dg; j < pdeg; ++j) csr[start + j] = -1;   // <=7 pads per node
    __syncthreads();
    for (int e = e0r + t; e < e1r; e += 512) {
        unsigned w = part[e];
        int dl = (int)(w & 511u);
        int p = atomicAdd(&cur[dl], 1);
        csr[p] = (int)(w >> 9);
    }
}

// ---------------- GEMM1 (MFMA): Hs1 = bf16((x @ W1) * isq[row]) ----------------
// also zeroes sentinel row n (block 0).

__global__ __launch_bounds__(256) void k_gemm1(const float* __restrict__ x,
                                               const __bf16* __restrict__ W1t,
                                               const float* __restrict__ isq,
                                               unsigned short* __restrict__ out, int n) {
    if (blockIdx.x == 0 && threadIdx.x < 16) {
        int4 z = {0, 0, 0, 0};
        *(int4*)(out + (size_t)n * 128 + threadIdx.x * 8) = z;
    }
    const int lane = threadIdx.x & 63;
    const int wid  = blockIdx.x * 4 + (threadIdx.x >> 6);
    const int r0 = wid * 16;
    if (r0 >= n) return;
    const int mr = lane & 15;
    const int kg = lane >> 4;

    bf16x8 af[4];
    const float* xrow = x + (size_t)(r0 + mr) * 128 + kg * 8;
    #pragma unroll
    for (int s = 0; s < 4; ++s) {
        f32x4 u0 = *(const f32x4*)(xrow + s * 32);
        f32x4 u1 = *(const f32x4*)(xrow + s * 32 + 4);
        bf16x8 a;
        a[0] = (__bf16)u0[0]; a[1] = (__bf16)u0[1]; a[2] = (__bf16)u0[2]; a[3] = (__bf16)u0[3];
        a[4] = (__bf16)u1[0]; a[5] = (__bf16)u1[1]; a[6] = (__bf16)u1[2]; a[7] = (__bf16)u1[3];
        af[s] = a;
    }
    float sc[4];
    #pragma unroll
    for (int r = 0; r < 4; ++r) sc[r] = isq[r0 + kg * 4 + r];

    #pragma unroll
    for (int nt = 0; nt < 8; ++nt) {
        const __bf16* wp = W1t + (size_t)(nt * 16 + mr) * 128 + kg * 8;
        f32x4 acc = {0.f, 0.f, 0.f, 0.f};
        #pragma unroll
        for (int s = 0; s < 4; ++s) {
            bf16x8 bfr = *(const bf16x8*)(wp + s * 32);
            acc = __builtin_amdgcn_mfma_f32_16x16x32_bf16(af[s], bfr, acc, 0, 0, 0);
        }
        #pragma unroll
        for (int r = 0; r < 4; ++r) {
            int row = r0 + kg * 4 + r;
            out[(size_t)row * 128 + nt * 16 + mr] = f2b(acc[r] * sc[r]);
        }
    }
}

// ------- agg1: wave/node, 16 lanes x 16B per edge row, 4 edges/iter -------
// zero-row sentinel; XCD-swizzled node assignment (contiguous nodes -> one XCD
// so each XCD's csr/offs/isq slice is L2-resident and read once).

__global__ __launch_bounds__(256) void k_agg1(const unsigned short* __restrict__ Hs,
                                              const int* __restrict__ csr,
                                              const int* __restrict__ offs,
                                              const int* __restrict__ nchk,
                                              const float* __restrict__ isq,
                                              const float* __restrict__ b1,
                                              unsigned short* __restrict__ out, int n) {
    const int sb = xcd_swizzle(blockIdx.x, gridDim.x);
    const int wid = sb * 4 + (threadIdx.x >> 6);
    if (wid >= n) return;
    const int lane = threadIdx.x & 63;
    const int g = lane >> 4, p = lane & 15;   // edge slot, 16B piece
    const int d = wid;
    const int e0 = offs[d];
    const int nc = nchk[d];                   // chunks of 4 edges

    float acc[8] = {0.f, 0.f, 0.f, 0.f, 0.f, 0.f, 0.f, 0.f};
    if (g == 0) {  // self loop
        int4 w = *(const int4*)(Hs + (size_t)d * 128 + p * 8);
        acc[0] = b2f_lo((unsigned)w.x); acc[1] = b2f_hi((unsigned)w.x);
        acc[2] = b2f_lo((unsigned)w.y); acc[3] = b2f_hi((unsigned)w.y);
        acc[4] = b2f_lo((unsigned)w.z); acc[5] = b2f_hi((unsigned)w.z);
        acc[6] = b2f_lo((unsigned)w.w); acc[7] = b2f_hi((unsigned)w.w);
    }

    #pragma unroll 4
    for (int c = 0; c < nc; ++c) {
        int cur = csr[e0 + 4 * c + g];
        unsigned srow = min((unsigned)cur, (unsigned)n);   // -1 -> zero row n
        int4 w = *(const int4*)(Hs + (size_t)srow * 128 + p * 8);
        acc[0] += b2f_lo((unsigned)w.x); acc[1] += b2f_hi((unsigned)w.x);
        acc[2] += b2f_lo((unsigned)w.y); acc[3] += b2f_hi((unsigned)w.y);
        acc[4] += b2f_lo((unsigned)w.z); acc[5] += b2f_hi((unsigned)w.z);
        acc[6] += b2f_lo((unsigned)w.w); acc[7] += b2f_hi((unsigned)w.w);
    }
    #pragma unroll
    for (int j = 0; j < 8; ++j) {
        acc[j] += __shfl_xor(acc[j], 16, 64);
        acc[j] += __shfl_xor(acc[j], 32, 64);
    }
    if (g == 0) {
        const float s = isq[d];
        f32x4 bb0 = *(const f32x4*)(b1 + p * 8);
        f32x4 bb1 = *(const f32x4*)(b1 + p * 8 + 4);
        unsigned short o[8];
        o[0] = f2b(fmaxf(fmaf(acc[0], s, bb0[0]), 0.f));
        o[1] = f2b(fmaxf(fmaf(acc[1], s, bb0[1]), 0.f));
        o[2] = f2b(fmaxf(fmaf(acc[2], s, bb0[2]), 0.f));
        o[3] = f2b(fmaxf(fmaf(acc[3], s, bb0[3]), 0.f));
        o[4] = f2b(fmaxf(fmaf(acc[4], s, bb1[0]), 0.f));
        o[5] = f2b(fmaxf(fmaf(acc[5], s, bb1[1]), 0.f));
        o[6] = f2b(fmaxf(fmaf(acc[6], s, bb1[2]), 0.f));
        o[7] = f2b(fmaxf(fmaf(acc[7], s, bb1[3]), 0.f));
        int4 r;
        r.x = (int)((unsigned)o[0] | ((unsigned)o[1] << 16));
        r.y = (int)((unsigned)o[2] | ((unsigned)o[3] << 16));
        r.z = (int)((unsigned)o[4] | ((unsigned)o[5] << 16));
        r.w = (int)((unsigned)o[6] | ((unsigned)o[7] << 16));
        *(int4*)(out + (size_t)d * 128 + p * 8) = r;
    }
}

// ------- GEMM2 (MFMA): Hs2 = bf16((H1 @ W2pad64) * isq[row]), 64-wide out ----
// also zeroes sentinel row n (block 0).

__global__ __launch_bounds__(256) void k_gemm2(const __bf16* __restrict__ h,
                                               const __bf16* __restrict__ W2t,
                                               const float* __restrict__ isq,
                                               unsigned short* __restrict__ out, int n) {
    if (blockIdx.x == 0 && threadIdx.x < 8) {
        int4 z = {0, 0, 0, 0};
        *(int4*)(out + (size_t)n * 64 + threadIdx.x * 8) = z;
    }
    const int lane = threadIdx.x & 63;
    const int wid  = blockIdx.x * 4 + (threadIdx.x >> 6);
    const int r0 = wid * 16;
    if (r0 >= n) return;
    const int mr = lane & 15;
    const int kg = lane >> 4;

    bf16x8 af[4];
    const __bf16* hrow = h + (size_t)(r0 + mr) * 128 + kg * 8;
    #pragma unroll
    for (int s = 0; s < 4; ++s) af[s] = *(const bf16x8*)(hrow + s * 32);
    float sc[4];
    #pragma unroll
    for (int r = 0; r < 4; ++r) sc[r] = isq[r0 + kg * 4 + r];

    #pragma unroll
    for (int nt = 0; nt < 4; ++nt) {
        const __bf16* wp = W2t + (size_t)(nt * 16 + mr) * 128 + kg * 8;
        f32x4 acc = {0.f, 0.f, 0.f, 0.f};
        #pragma unroll
        for (int s = 0; s < 4; ++s) {
            bf16x8 bfr = *(const bf16x8*)(wp + s * 32);
            acc = __builtin_amdgcn_mfma_f32_16x16x32_bf16(af[s], bfr, acc, 0, 0, 0);
        }
        int col = nt * 16 + mr;
        #pragma unroll
        for (int r = 0; r < 4; ++r) {
            int row = r0 + kg * 4 + r;
            out[(size_t)row * 64 + col] = f2b(acc[r] * sc[r]);
        }
    }
}

// ------- agg2: wave/node, 8 lanes x 16B per edge row, 8 edges/iter -------
// XCD-swizzled node assignment (same rationale as agg1).

__global__ __launch_bounds__(256) void k_agg2(const unsigned short* __restrict__ Hs,
                                              const int* __restrict__ csr,
                                              const int* __restrict__ offs,
                                              const int* __restrict__ nchk,
                                              const float* __restrict__ isq,
                                              const float* __restrict__ b2,
                                              float* __restrict__ out, int n) {
    const int sb = xcd_swizzle(blockIdx.x, gridDim.x);
    const int wid = sb * 4 + (threadIdx.x >> 6);
    if (wid >= n) return;
    const int lane = threadIdx.x & 63;
    const int g = lane >> 3, p = lane & 7;    // edge slot (8), 16B piece (8)
    const int d = wid;
    const int e0 = offs[d];
    const int nc8 = nchk[d] >> 1;             // chunks of 8 (padded x8)

    float acc[8];
    #pragma unroll
    for (int j = 0; j < 8; ++j) acc[j] = 0.f;
    if (g == 0) {   // self
        int4 w = *(const int4*)(Hs + (size_t)d * 64 + p * 8);
        acc[0] = b2f_lo((unsigned)w.x); acc[1] = b2f_hi((unsigned)w.x);
        acc[2] = b2f_lo((unsigned)w.y); acc[3] = b2f_hi((unsigned)w.y);
        acc[4] = b2f_lo((unsigned)w.z); acc[5] = b2f_hi((unsigned)w.z);
        acc[6] = b2f_lo((unsigned)w.w); acc[7] = b2f_hi((unsigned)w.w);
    }
    #pragma unroll 4
    for (int c = 0; c < nc8; ++c) {
        int cur = csr[e0 + 8 * c + g];
        unsigned srow = min((unsigned)cur, (unsigned)n);   // -1 -> zero row n
        int4 w = *(const int4*)(Hs + (size_t)srow * 64 + p * 8);
        acc[0] += b2f_lo((unsigned)w.x); acc[1] += b2f_hi((unsigned)w.x);
        acc[2] += b2f_lo((unsigned)w.y); acc[3] += b2f_hi((unsigned)w.y);
        acc[4] += b2f_lo((unsigned)w.z); acc[5] += b2f_hi((unsigned)w.z);
        acc[6] += b2f_lo((unsigned)w.w); acc[7] += b2f_hi((unsigned)w.w);
    }
    #pragma unroll
    for (int j = 0; j < 8; ++j) {
        acc[j] += __shfl_xor(acc[j], 8, 64);
        acc[j] += __shfl_xor(acc[j], 16, 64);
        acc[j] += __shfl_xor(acc[j], 32, 64);
    }
    if (g == 0) {
        const float s = isq[d];
        const bool real = p < 5;              // lanes 0..4 hold ch 0..39
        float v[8];
        if (real) {
            f32x4 b0 = *(const f32x4*)(b2 + p * 8);
            f32x4 b1v = *(const f32x4*)(b2 + p * 8 + 4);
            v[0] = fmaf(acc[0], s, b0[0]);  v[1] = fmaf(acc[1], s, b0[1]);
            v[2] = fmaf(acc[2], s, b0[2]);  v[3] = fmaf(acc[3], s, b0[3]);
            v[4] = fmaf(acc[4], s, b1v[0]); v[5] = fmaf(acc[5], s, b1v[1]);
            v[6] = fmaf(acc[6], s, b1v[2]); v[7] = fmaf(acc[7], s, b1v[3]);
        } else {
            #pragma unroll
            for (int j = 0; j < 8; ++j) v[j] = -INFINITY;
        }
        float lm = v[0];
        #pragma unroll
        for (int j = 1; j < 8; ++j) lm = fmaxf(lm, v[j]);
        lm = fmaxf(lm, __shfl_xor(lm, 1, 64));
        lm = fmaxf(lm, __shfl_xor(lm, 2, 64));
        lm = fmaxf(lm, __shfl_xor(lm, 4, 64));
        float es = 0.f;
        if (real) {
            #pragma unroll
            for (int j = 0; j < 8; ++j) es += expf(v[j] - lm);
        }
        es += __shfl_xor(es, 1, 64);
        es += __shfl_xor(es, 2, 64);
        es += __shfl_xor(es, 4, 64);
        float lse = lm + logf(es);
        if (real) {
            f32x4 r0, r1;
            r0[0] = v[0] - lse; r0[1] = v[1] - lse; r0[2] = v[2] - lse; r0[3] = v[3] - lse;
            r1[0] = v[4] - lse; r1[1] = v[5] - lse; r1[2] = v[6] - lse; r1[3] = v[7] - lse;
            float* op = out + (size_t)d * 40 + p * 8;
            *(f32x4*)op = r0;
            *(f32x4*)(op + 4) = r1;
        }
    }
}

// ---------------- launch ----------------

extern "C" void kernel_launch(void* const* d_in, const int* in_sizes, int n_in,
                              void* d_out, int out_size, void* d_ws, size_t ws_size,
                              hipStream_t stream) {
    const float* x  = (const float*)d_in[0];
    const int*   ei = (const int*)d_in[1];
    const float* W1 = (const float*)d_in[2];
    const float* b1 = (const float*)d_in[3];
    const float* W2 = (const float*)d_in[4];
    const float* b2 = (const float*)d_in[5];
    float* out = (float*)d_out;

    const int N = in_sizes[0] / 128;
    const int E = in_sizes[1] / 2;
    const int* srcA = ei;
    const int* dstA = ei + E;
    const int nbuk = (N + 511) >> 9;
    const int chunk = (E + NB_SC - 1) / NB_SC;
    const int M = nbuk * NB_SC;
    int per = (M + 1023) >> 10;
    per = (per + 3) & ~3;
    const int Mpad = per * 1024;
    const int csrCap = E + nbuk * BUKPAD + 64;

    char* ws = (char*)d_ws;
    size_t off = 0;
    auto alloc = [&](size_t bytes) -> void* {
        void* p = ws + off;
        off += (bytes + 255) & ~(size_t)255;
        return p;
    };
    int*      hist = (int*)alloc((size_t)Mpad * 4);
    unsigned* part = (unsigned*)alloc((size_t)E * 4);
    int*      offs = (int*)alloc((size_t)N * 4);
    int*      nchk = (int*)alloc((size_t)N * 4);
    float*    isq  = (float*)alloc((size_t)N * 4);
    int*      csr  = (int*)alloc((size_t)csrCap * 4);
    __bf16*   W1t  = (__bf16*)alloc(128 * 128 * 2);
    __bf16*   W2t  = (__bf16*)alloc(64 * 128 * 2);
    unsigned short* Hs1 = (unsigned short*)alloc((size_t)(N + 8) * 128 * 2);  // +zero row
    unsigned short* H1  = (unsigned short*)alloc((size_t)N * 128 * 2);
    unsigned short* Hs2 = (unsigned short*)alloc((size_t)(N + 8) * 64 * 2);   // +zero row

    k_hist<<<NB_SC, 256, 0, stream>>>(dstA, hist, E, nbuk, chunk,
                                      W1, W2, W1t, W2t, M, Mpad);
    k_scan_hist<<<1, 1024, 0, stream>>>(hist, per);
    k_scatter<<<NB_SC, 256, 0, stream>>>(srcA, dstA, hist, part, E, nbuk, chunk);
    k_lcsr<<<nbuk, 512, 0, stream>>>(part, hist, csr, offs, nchk, isq, E, N, nbuk);

    const int nwav = (N + 15) / 16;
    k_gemm1<<<(nwav + 3) / 4, 256, 0, stream>>>(x, W1t, isq, Hs1, N);
    k_agg1<<<(N + 3) / 4, 256, 0, stream>>>(Hs1, csr, offs, nchk, isq, b1, H1, N);
    k_gemm2<<<(nwav + 3) / 4, 256, 0, stream>>>((const __bf16*)H1, W2t, isq, Hs2, N);
    k_agg2<<<(N + 3) / 4, 256, 0, stream>>>(Hs2, csr, offs, nchk, isq, b2, out, N);
}

// Round 13
// 223.539 us; speedup vs baseline: 1.8240x; 1.0906x over previous
//
#include <hip/hip_runtime.h>
#include <hip/hip_bf16.h>
#include <math.h>

typedef __bf16 bf16x8 __attribute__((ext_vector_type(8)));
typedef float  f32x4  __attribute__((ext_vector_type(4)));

__device__ __forceinline__ unsigned short f2b(float f) {
    union { float f; unsigned u; } v; v.f = f;
    unsigned r = v.u + 0x7fffu + ((v.u >> 16) & 1u);   // RNE
    return (unsigned short)(r >> 16);
}
__device__ __forceinline__ float b2f_lo(unsigned u) {
    union { unsigned u; float f; } v; v.u = u << 16; return v.f;
}
__device__ __forceinline__ float b2f_hi(unsigned u) {
    union { unsigned u; float f; } v; v.u = u & 0xffff0000u; return v.f;
}
// bijective XCD swizzle (m204): contiguous ranges of blocks -> one XCD
__device__ __forceinline__ int xcd_swizzle(int bid, int nwg) {
    int xcd = bid & 7, loc = bid >> 3;
    int q = nwg >> 3, r = nwg & 7;
    int base = (xcd < r) ? xcd * (q + 1) : r * (q + 1) + (xcd - r) * q;
    return base + loc;
}

// ================= CSR build: two-level counting sort (LDS atomics only) ====
// csr PADDED: each node's list 8-aligned, length rounded to x8, pads = -1.
// nchk[i] = padded length / 4.

#define NB_SC 128
#define BUKPAD 3584   // max padding per 512-node bucket (7 per node), 8-divisible

// hist + fused weight-prep (bf16 transpose) + hist zero-pad
__global__ __launch_bounds__(256) void k_hist(const int* __restrict__ dstA,
                                              int* __restrict__ hist_g,
                                              int E, int nbuk, int chunk,
                                              const float* __restrict__ W1,
                                              const float* __restrict__ W2,
                                              __bf16* __restrict__ W1t,
                                              __bf16* __restrict__ W2t,
                                              int M, int Mpad) {
    __shared__ int h[256];
    const int t = threadIdx.x, b = blockIdx.x;
    h[t] = 0;
    __syncthreads();
    const int e0 = b * chunk, e1 = min(E, e0 + chunk);
    for (int e = e0 + t; e < e1; e += 256) atomicAdd(&h[dstA[e] >> 9], 1);
    const int gid = b * 256 + t;
    for (int idx = gid; idx < 128 * 128; idx += NB_SC * 256) {
        int k = idx >> 7, c = idx & 127;
        W1t[c * 128 + k] = (__bf16)W1[idx];
    }
    for (int idx = gid; idx < 64 * 128; idx += NB_SC * 256) {
        int c = idx >> 7, k = idx & 127;
        W2t[idx] = (c < 40) ? (__bf16)W2[k * 40 + c] : (__bf16)0.f;
    }
    for (int idx = M + gid; idx < Mpad; idx += NB_SC * 256) hist_g[idx] = 0;
    __syncthreads();
    if (t < nbuk) hist_g[t * NB_SC + b] = h[t];
}

__global__ __launch_bounds__(1024) void k_scan_hist(int* __restrict__ hist, int per) {
    __shared__ int ts[1024];
    const int t = threadIdx.x;
    const int base = t * per;
    int4 v[16];
    const int nv = per >> 2;
    int sum = 0;
    #pragma unroll 4
    for (int j = 0; j < nv; ++j) {
        v[j] = *(const int4*)(hist + base + j * 4);
        sum += v[j].x + v[j].y + v[j].z + v[j].w;
    }
    ts[t] = sum;
    __syncthreads();
    for (int o = 1; o < 1024; o <<= 1) {
        int a = (t >= o) ? ts[t - o] : 0;
        __syncthreads();
        ts[t] += a;
        __syncthreads();
    }
    int run = (t == 0) ? 0 : ts[t - 1];
    #pragma unroll 4
    for (int j = 0; j < nv; ++j) {
        int a;
        a = v[j].x; v[j].x = run; run += a;
        a = v[j].y; v[j].y = run; run += a;
        a = v[j].z; v[j].z = run; run += a;
        a = v[j].w; v[j].w = run; run += a;
        *(int4*)(hist + base + j * 4) = v[j];
    }
}

__global__ __launch_bounds__(256) void k_scatter(const int* __restrict__ srcA,
                                                 const int* __restrict__ dstA,
                                                 const int* __restrict__ base,
                                                 unsigned* __restrict__ part,
                                                 int E, int nbuk, int chunk) {
    __shared__ int cur[256];
    const int t = threadIdx.x, b = blockIdx.x;
    if (t < nbuk) cur[t] = base[t * NB_SC + b];
    __syncthreads();
    const int e0 = b * chunk, e1 = min(E, e0 + chunk);
    for (int e = e0 + t; e < e1; e += 256) {
        int d = dstA[e];
        int s = srcA[e];
        int buk = d >> 9;
        int p = atomicAdd(&cur[buk], 1);
        part[p] = ((unsigned)s << 9) | (unsigned)(d & 511);
    }
}

// per-bucket: count -> padded scan -> fill padded csr (+ -1 pads); offs/nchk/isq
__global__ __launch_bounds__(512) void k_lcsr(const unsigned* __restrict__ part,
                                              const int* __restrict__ base,
                                              int* __restrict__ csr,
                                              int* __restrict__ offs,
                                              int* __restrict__ nchk,
                                              float* __restrict__ isq,
                                              int E, int N, int nbuk) {
    __shared__ int deg[512];
    __shared__ int sc[512];
    __shared__ int cur[512];
    const int t = threadIdx.x, buk = blockIdx.x;
    const int n0 = buk << 9;
    const int nn = min(512, N - n0);
    const int e0r = base[buk * NB_SC];
    const int e1r = (buk + 1 < nbuk) ? base[(buk + 1) * NB_SC] : E;
    deg[t] = 0;
    __syncthreads();
    for (int e = e0r + t; e < e1r; e += 512) atomicAdd(&deg[part[e] & 511], 1);
    __syncthreads();
    const int dg = deg[t];
    const int pdeg = (dg + 7) & ~7;
    sc[t] = pdeg;
    __syncthreads();
    for (int o = 1; o < 512; o <<= 1) {
        int a = (t >= o) ? sc[t - o] : 0;
        __syncthreads();
        sc[t] += a;
        __syncthreads();
    }
    const int excl = (t == 0) ? 0 : sc[t - 1];
    const int pbase = ((e0r + 7) & ~7) + buk * BUKPAD;
    const int start = pbase + excl;
    cur[t] = start;
    if (t < nn) {
        offs[n0 + t] = start;
        nchk[n0 + t] = pdeg >> 2;
        isq[n0 + t]  = rsqrtf((float)(dg + 1));
    }
    for (int j = dg; j < pdeg; ++j) csr[start + j] = -1;   // <=7 pads per node
    __syncthreads();
    for (int e = e0r + t; e < e1r; e += 512) {
        unsigned w = part[e];
        int dl = (int)(w & 511u);
        int p = atomicAdd(&cur[dl], 1);
        csr[p] = (int)(w >> 9);
    }
}

// ---------------- GEMM1 (MFMA): Hs1 = bf16((x @ W1) * isq[row]) ----------------
// also zeroes sentinel row n (block 0).

__global__ __launch_bounds__(256) void k_gemm1(const float* __restrict__ x,
                                               const __bf16* __restrict__ W1t,
                                               const float* __restrict__ isq,
                                               unsigned short* __restrict__ out, int n) {
    if (blockIdx.x == 0 && threadIdx.x < 16) {
        int4 z = {0, 0, 0, 0};
        *(int4*)(out + (size_t)n * 128 + threadIdx.x * 8) = z;
    }
    const int lane = threadIdx.x & 63;
    const int wid  = blockIdx.x * 4 + (threadIdx.x >> 6);
    const int r0 = wid * 16;
    if (r0 >= n) return;
    const int mr = lane & 15;
    const int kg = lane >> 4;

    bf16x8 af[4];
    const float* xrow = x + (size_t)(r0 + mr) * 128 + kg * 8;
    #pragma unroll
    for (int s = 0; s < 4; ++s) {
        f32x4 u0 = *(const f32x4*)(xrow + s * 32);
        f32x4 u1 = *(const f32x4*)(xrow + s * 32 + 4);
        bf16x8 a;
        a[0] = (__bf16)u0[0]; a[1] = (__bf16)u0[1]; a[2] = (__bf16)u0[2]; a[3] = (__bf16)u0[3];
        a[4] = (__bf16)u1[0]; a[5] = (__bf16)u1[1]; a[6] = (__bf16)u1[2]; a[7] = (__bf16)u1[3];
        af[s] = a;
    }
    float sc[4];
    #pragma unroll
    for (int r = 0; r < 4; ++r) sc[r] = isq[r0 + kg * 4 + r];

    #pragma unroll
    for (int nt = 0; nt < 8; ++nt) {
        const __bf16* wp = W1t + (size_t)(nt * 16 + mr) * 128 + kg * 8;
        f32x4 acc = {0.f, 0.f, 0.f, 0.f};
        #pragma unroll
        for (int s = 0; s < 4; ++s) {
            bf16x8 bfr = *(const bf16x8*)(wp + s * 32);
            acc = __builtin_amdgcn_mfma_f32_16x16x32_bf16(af[s], bfr, acc, 0, 0, 0);
        }
        #pragma unroll
        for (int r = 0; r < 4; ++r) {
            int row = r0 + kg * 4 + r;
            out[(size_t)row * 128 + nt * 16 + mr] = f2b(acc[r] * sc[r]);
        }
    }
}

// ------- agg1: wave/node, 16 lanes x 16B per edge row, 4 edges/iter -------
// zero-row sentinel; XCD-swizzled node assignment. AT LINE-RATE ROOFLINE.

__global__ __launch_bounds__(256) void k_agg1(const unsigned short* __restrict__ Hs,
                                              const int* __restrict__ csr,
                                              const int* __restrict__ offs,
                                              const int* __restrict__ nchk,
                                              const float* __restrict__ isq,
                                              const float* __restrict__ b1,
                                              unsigned short* __restrict__ out, int n) {
    const int sb = xcd_swizzle(blockIdx.x, gridDim.x);
    const int wid = sb * 4 + (threadIdx.x >> 6);
    if (wid >= n) return;
    const int lane = threadIdx.x & 63;
    const int g = lane >> 4, p = lane & 15;   // edge slot, 16B piece
    const int d = wid;
    const int e0 = offs[d];
    const int nc = nchk[d];                   // chunks of 4 edges

    float acc[8] = {0.f, 0.f, 0.f, 0.f, 0.f, 0.f, 0.f, 0.f};
    if (g == 0) {  // self loop
        int4 w = *(const int4*)(Hs + (size_t)d * 128 + p * 8);
        acc[0] = b2f_lo((unsigned)w.x); acc[1] = b2f_hi((unsigned)w.x);
        acc[2] = b2f_lo((unsigned)w.y); acc[3] = b2f_hi((unsigned)w.y);
        acc[4] = b2f_lo((unsigned)w.z); acc[5] = b2f_hi((unsigned)w.z);
        acc[6] = b2f_lo((unsigned)w.w); acc[7] = b2f_hi((unsigned)w.w);
    }

    #pragma unroll 4
    for (int c = 0; c < nc; ++c) {
        int cur = csr[e0 + 4 * c + g];
        unsigned srow = min((unsigned)cur, (unsigned)n);   // -1 -> zero row n
        int4 w = *(const int4*)(Hs + (size_t)srow * 128 + p * 8);
        acc[0] += b2f_lo((unsigned)w.x); acc[1] += b2f_hi((unsigned)w.x);
        acc[2] += b2f_lo((unsigned)w.y); acc[3] += b2f_hi((unsigned)w.y);
        acc[4] += b2f_lo((unsigned)w.z); acc[5] += b2f_hi((unsigned)w.z);
        acc[6] += b2f_lo((unsigned)w.w); acc[7] += b2f_hi((unsigned)w.w);
    }
    #pragma unroll
    for (int j = 0; j < 8; ++j) {
        acc[j] += __shfl_xor(acc[j], 16, 64);
        acc[j] += __shfl_xor(acc[j], 32, 64);
    }
    if (g == 0) {
        const float s = isq[d];
        f32x4 bb0 = *(const f32x4*)(b1 + p * 8);
        f32x4 bb1 = *(const f32x4*)(b1 + p * 8 + 4);
        unsigned short o[8];
        o[0] = f2b(fmaxf(fmaf(acc[0], s, bb0[0]), 0.f));
        o[1] = f2b(fmaxf(fmaf(acc[1], s, bb0[1]), 0.f));
        o[2] = f2b(fmaxf(fmaf(acc[2], s, bb0[2]), 0.f));
        o[3] = f2b(fmaxf(fmaf(acc[3], s, bb0[3]), 0.f));
        o[4] = f2b(fmaxf(fmaf(acc[4], s, bb1[0]), 0.f));
        o[5] = f2b(fmaxf(fmaf(acc[5], s, bb1[1]), 0.f));
        o[6] = f2b(fmaxf(fmaf(acc[6], s, bb1[2]), 0.f));
        o[7] = f2b(fmaxf(fmaf(acc[7], s, bb1[3]), 0.f));
        int4 r;
        r.x = (int)((unsigned)o[0] | ((unsigned)o[1] << 16));
        r.y = (int)((unsigned)o[2] | ((unsigned)o[3] << 16));
        r.z = (int)((unsigned)o[4] | ((unsigned)o[5] << 16));
        r.w = (int)((unsigned)o[6] | ((unsigned)o[7] << 16));
        *(int4*)(out + (size_t)d * 128 + p * 8) = r;
    }
}

// ------- GEMM2 (MFMA): Hs2 = bf16((H1 @ W2pad64) * isq[row]), 64-wide out ----
// also zeroes sentinel row n (block 0).

__global__ __launch_bounds__(256) void k_gemm2(const __bf16* __restrict__ h,
                                               const __bf16* __restrict__ W2t,
                                               const float* __restrict__ isq,
                                               unsigned short* __restrict__ out, int n) {
    if (blockIdx.x == 0 && threadIdx.x < 8) {
        int4 z = {0, 0, 0, 0};
        *(int4*)(out + (size_t)n * 64 + threadIdx.x * 8) = z;
    }
    const int lane = threadIdx.x & 63;
    const int wid  = blockIdx.x * 4 + (threadIdx.x >> 6);
    const int r0 = wid * 16;
    if (r0 >= n) return;
    const int mr = lane & 15;
    const int kg = lane >> 4;

    bf16x8 af[4];
    const __bf16* hrow = h + (size_t)(r0 + mr) * 128 + kg * 8;
    #pragma unroll
    for (int s = 0; s < 4; ++s) af[s] = *(const bf16x8*)(hrow + s * 32);
    float sc[4];
    #pragma unroll
    for (int r = 0; r < 4; ++r) sc[r] = isq[r0 + kg * 4 + r];

    #pragma unroll
    for (int nt = 0; nt < 4; ++nt) {
        const __bf16* wp = W2t + (size_t)(nt * 16 + mr) * 128 + kg * 8;
        f32x4 acc = {0.f, 0.f, 0.f, 0.f};
        #pragma unroll
        for (int s = 0; s < 4; ++s) {
            bf16x8 bfr = *(const bf16x8*)(wp + s * 32);
            acc = __builtin_amdgcn_mfma_f32_16x16x32_bf16(af[s], bfr, acc, 0, 0, 0);
        }
        int col = nt * 16 + mr;
        #pragma unroll
        for (int r = 0; r < 4; ++r) {
            int row = r0 + kg * 4 + r;
            out[(size_t)row * 64 + col] = f2b(acc[r] * sc[r]);
        }
    }
}

// ------- agg2: 8 nodes/wave, 8-lane group per node, serial edge loop --------
// Each lane owns 8 ch of its group's node -> NO accumulate reduction; softmax
// epilogue amortized over 8 nodes per wave. csr read is group-uniform.

__global__ __launch_bounds__(256) void k_agg2(const unsigned short* __restrict__ Hs,
                                              const int* __restrict__ csr,
                                              const int* __restrict__ offs,
                                              const int* __restrict__ nchk,
                                              const float* __restrict__ isq,
                                              const float* __restrict__ b2,
                                              float* __restrict__ out, int n) {
    const int sb = xcd_swizzle(blockIdx.x, gridDim.x);
    const int lane = threadIdx.x & 63;
    const int grp = lane >> 3;                 // node sub-index 0..7
    const int q = lane & 7;                    // 16B piece of the 128B row
    const int d = (sb * 4 + (threadIdx.x >> 6)) * 8 + grp;
    if (d >= n) return;
    const int e0 = offs[d];
    const int ne = nchk[d] << 2;               // padded length (x8)

    float acc[8];
    {   // self row — each group its own node, all lanes active, no duplication
        int4 w = *(const int4*)(Hs + (size_t)d * 64 + q * 8);
        acc[0] = b2f_lo((unsigned)w.x); acc[1] = b2f_hi((unsigned)w.x);
        acc[2] = b2f_lo((unsigned)w.y); acc[3] = b2f_hi((unsigned)w.y);
        acc[4] = b2f_lo((unsigned)w.z); acc[5] = b2f_hi((unsigned)w.z);
        acc[6] = b2f_lo((unsigned)w.w); acc[7] = b2f_hi((unsigned)w.w);
    }
    #pragma unroll 2
    for (int e = 0; e < ne; ++e) {
        int cur = csr[e0 + e];                 // group-uniform address
        unsigned srow = min((unsigned)cur, (unsigned)n);   // -1 -> zero row n
        int4 w = *(const int4*)(Hs + (size_t)srow * 64 + q * 8);
        acc[0] += b2f_lo((unsigned)w.x); acc[1] += b2f_hi((unsigned)w.x);
        acc[2] += b2f_lo((unsigned)w.y); acc[3] += b2f_hi((unsigned)w.y);
        acc[4] += b2f_lo((unsigned)w.z); acc[5] += b2f_hi((unsigned)w.z);
        acc[6] += b2f_lo((unsigned)w.w); acc[7] += b2f_hi((unsigned)w.w);
    }

    // softmax over 40 real ch: lanes q=0..4 hold ch q*8..q*8+7
    const float s = isq[d];
    const bool real = q < 5;
    const int qb = real ? q : 4;               // avoid OOB read of b2[40..]
    f32x4 b0 = *(const f32x4*)(b2 + qb * 8);
    f32x4 b1v = *(const f32x4*)(b2 + qb * 8 + 4);
    float v[8];
    v[0] = fmaf(acc[0], s, b0[0]);  v[1] = fmaf(acc[1], s, b0[1]);
    v[2] = fmaf(acc[2], s, b0[2]);  v[3] = fmaf(acc[3], s, b0[3]);
    v[4] = fmaf(acc[4], s, b1v[0]); v[5] = fmaf(acc[5], s, b1v[1]);
    v[6] = fmaf(acc[6], s, b1v[2]); v[7] = fmaf(acc[7], s, b1v[3]);

    float lm = -INFINITY;
    if (real) {
        lm = v[0];
        #pragma unroll
        for (int j = 1; j < 8; ++j) lm = fmaxf(lm, v[j]);
    }
    lm = fmaxf(lm, __shfl_xor(lm, 1, 64));
    lm = fmaxf(lm, __shfl_xor(lm, 2, 64));
    lm = fmaxf(lm, __shfl_xor(lm, 4, 64));
    float es = 0.f;
    if (real) {
        #pragma unroll
        for (int j = 0; j < 8; ++j) es += expf(v[j] - lm);
    }
    es += __shfl_xor(es, 1, 64);
    es += __shfl_xor(es, 2, 64);
    es += __shfl_xor(es, 4, 64);
    const float lse = lm + logf(es);
    if (real) {
        f32x4 r0, r1;
        r0[0] = v[0] - lse; r0[1] = v[1] - lse; r0[2] = v[2] - lse; r0[3] = v[3] - lse;
        r1[0] = v[4] - lse; r1[1] = v[5] - lse; r1[2] = v[6] - lse; r1[3] = v[7] - lse;
        float* op = out + (size_t)d * 40 + q * 8;
        *(f32x4*)op = r0;
        *(f32x4*)(op + 4) = r1;
    }
}

// ---------------- launch ----------------

extern "C" void kernel_launch(void* const* d_in, const int* in_sizes, int n_in,
                              void* d_out, int out_size, void* d_ws, size_t ws_size,
                              hipStream_t stream) {
    const float* x  = (const float*)d_in[0];
    const int*   ei = (const int*)d_in[1];
    const float* W1 = (const float*)d_in[2];
    const float* b1 = (const float*)d_in[3];
    const float* W2 = (const float*)d_in[4];
    const float* b2 = (const float*)d_in[5];
    float* out = (float*)d_out;

    const int N = in_sizes[0] / 128;
    const int E = in_sizes[1] / 2;
    const int* srcA = ei;
    const int* dstA = ei + E;
    const int nbuk = (N + 511) >> 9;
    const int chunk = (E + NB_SC - 1) / NB_SC;
    const int M = nbuk * NB_SC;
    int per = (M + 1023) >> 10;
    per = (per + 3) & ~3;
    const int Mpad = per * 1024;
    const int csrCap = E + nbuk * BUKPAD + 64;

    char* ws = (char*)d_ws;
    size_t off = 0;
    auto alloc = [&](size_t bytes) -> void* {
        void* p = ws + off;
        off += (bytes + 255) & ~(size_t)255;
        return p;
    };
    int*      hist = (int*)alloc((size_t)Mpad * 4);
    unsigned* part = (unsigned*)alloc((size_t)E * 4);
    int*      offs = (int*)alloc((size_t)N * 4);
    int*      nchk = (int*)alloc((size_t)N * 4);
    float*    isq  = (float*)alloc((size_t)N * 4);
    int*      csr  = (int*)alloc((size_t)csrCap * 4);
    __bf16*   W1t  = (__bf16*)alloc(128 * 128 * 2);
    __bf16*   W2t  = (__bf16*)alloc(64 * 128 * 2);
    unsigned short* Hs1 = (unsigned short*)alloc((size_t)(N + 8) * 128 * 2);  // +zero row
    unsigned short* H1  = (unsigned short*)alloc((size_t)N * 128 * 2);
    unsigned short* Hs2 = (unsigned short*)alloc((size_t)(N + 8) * 64 * 2);   // +zero row

    k_hist<<<NB_SC, 256, 0, stream>>>(dstA, hist, E, nbuk, chunk,
                                      W1, W2, W1t, W2t, M, Mpad);
    k_scan_hist<<<1, 1024, 0, stream>>>(hist, per);
    k_scatter<<<NB_SC, 256, 0, stream>>>(srcA, dstA, hist, part, E, nbuk, chunk);
    k_lcsr<<<nbuk, 512, 0, stream>>>(part, hist, csr, offs, nchk, isq, E, N, nbuk);

    const int nwav = (N + 15) / 16;
    k_gemm1<<<(nwav + 3) / 4, 256, 0, stream>>>(x, W1t, isq, Hs1, N);
    k_agg1<<<(N + 3) / 4, 256, 0, stream>>>(Hs1, csr, offs, nchk, isq, b1, H1, N);
    k_gemm2<<<(nwav + 3) / 4, 256, 0, stream>>>((const __bf16*)H1, W2t, isq, Hs2, N);
    k_agg2<<<(N + 31) / 32, 256, 0, stream>>>(Hs2, csr, offs, nchk, isq, b2, out, N);
}

// Round 14
// 208.418 us; speedup vs baseline: 1.9563x; 1.0726x over previous
//
#include <hip/hip_runtime.h>
#include <hip/hip_bf16.h>
#include <math.h>

typedef __bf16 bf16x8 __attribute__((ext_vector_type(8)));
typedef float  f32x4  __attribute__((ext_vector_type(4)));

__device__ __forceinline__ unsigned short f2b(float f) {
    union { float f; unsigned u; } v; v.f = f;
    unsigned r = v.u + 0x7fffu + ((v.u >> 16) & 1u);   // RNE
    return (unsigned short)(r >> 16);
}
__device__ __forceinline__ float b2f_lo(unsigned u) {
    union { unsigned u; float f; } v; v.u = u << 16; return v.f;
}
__device__ __forceinline__ float b2f_hi(unsigned u) {
    union { unsigned u; float f; } v; v.u = u & 0xffff0000u; return v.f;
}
// bijective XCD swizzle (m204): contiguous ranges of blocks -> one XCD
__device__ __forceinline__ int xcd_swizzle(int bid, int nwg) {
    int xcd = bid & 7, loc = bid >> 3;
    int q = nwg >> 3, r = nwg & 7;
    int base = (xcd < r) ? xcd * (q + 1) : r * (q + 1) + (xcd - r) * q;
    return base + loc;
}

// ================= CSR build: two-level counting sort (LDS atomics only) ====
// csr PADDED: each node's list 8-aligned, length rounded to x8, pads = -1.
// nchk[i] = padded length / 4.
// R14: no separate scan kernel — each scatter block derives its own cursors
// from the hist matrix (redundant 100KB read + LDS scan), and block 0 emits
// the per-bucket prefix array (bukpre) consumed by k_lcsr.

#define NB_SC 128
#define BUKPAD 3584   // max padding per 512-node bucket (7 per node), 8-divisible

// hist + fused weight-prep (bf16 transpose)
__global__ __launch_bounds__(256) void k_hist(const int* __restrict__ dstA,
                                              int* __restrict__ hist_g,
                                              int E, int nbuk, int chunk,
                                              const float* __restrict__ W1,
                                              const float* __restrict__ W2,
                                              __bf16* __restrict__ W1t,
                                              __bf16* __restrict__ W2t) {
    __shared__ int h[256];
    const int t = threadIdx.x, b = blockIdx.x;
    h[t] = 0;
    __syncthreads();
    const int e0 = b * chunk, e1 = min(E, e0 + chunk);
    for (int e = e0 + t; e < e1; e += 256) atomicAdd(&h[dstA[e] >> 9], 1);
    const int gid = b * 256 + t;
    for (int idx = gid; idx < 128 * 128; idx += NB_SC * 256) {
        int k = idx >> 7, c = idx & 127;
        W1t[c * 128 + k] = (__bf16)W1[idx];
    }
    for (int idx = gid; idx < 64 * 128; idx += NB_SC * 256) {
        int c = idx >> 7, k = idx & 127;
        W2t[idx] = (c < 40) ? (__bf16)W2[k * 40 + c] : (__bf16)0.f;
    }
    __syncthreads();
    if (t < nbuk) hist_g[t * NB_SC + b] = h[t];
}

// scatter with self-computed cursors (replaces the single-block scan kernel)
__global__ __launch_bounds__(256) void k_scatter(const int* __restrict__ srcA,
                                                 const int* __restrict__ dstA,
                                                 const int* __restrict__ hist,
                                                 int* __restrict__ bukpre,
                                                 unsigned* __restrict__ part,
                                                 int E, int nbuk, int chunk) {
    __shared__ int rowpart[256];   // sum of hist[buk][0..b-1]
    __shared__ int sc[256];        // bucket totals -> inclusive prefix
    __shared__ int cur[256];
    const int t = threadIdx.x, b = blockIdx.x;
    int tot = 0, rp = 0;
    if (t < nbuk) {
        const int* row = hist + t * NB_SC;
        #pragma unroll 8
        for (int i = 0; i < NB_SC; ++i) {
            int v = row[i];
            tot += v;
            rp += (i < b) ? v : 0;
        }
    }
    rowpart[t] = rp;
    sc[t] = tot;
    __syncthreads();
    for (int o = 1; o < 256; o <<= 1) {
        int a = (t >= o) ? sc[t - o] : 0;
        __syncthreads();
        sc[t] += a;
        __syncthreads();
    }
    const int excl = (t == 0) ? 0 : sc[t - 1];
    cur[t] = excl + rowpart[t];
    if (b == 0) {
        if (t < nbuk) bukpre[t] = excl;
        if (t == 0) bukpre[nbuk] = sc[255];   // total = E
    }
    __syncthreads();
    const int e0 = b * chunk, e1 = min(E, e0 + chunk);
    for (int e = e0 + t; e < e1; e += 256) {
        int d = dstA[e];
        int s = srcA[e];
        int buk = d >> 9;
        int p = atomicAdd(&cur[buk], 1);
        part[p] = ((unsigned)s << 9) | (unsigned)(d & 511);
    }
}

// per-bucket: count -> padded scan -> fill padded csr (+ -1 pads); offs/nchk/isq
__global__ __launch_bounds__(512) void k_lcsr(const unsigned* __restrict__ part,
                                              const int* __restrict__ bukpre,
                                              int* __restrict__ csr,
                                              int* __restrict__ offs,
                                              int* __restrict__ nchk,
                                              float* __restrict__ isq,
                                              int E, int N, int nbuk) {
    __shared__ int deg[512];
    __shared__ int sc[512];
    __shared__ int cur[512];
    const int t = threadIdx.x, buk = blockIdx.x;
    const int n0 = buk << 9;
    const int nn = min(512, N - n0);
    const int e0r = bukpre[buk];
    const int e1r = bukpre[buk + 1];
    deg[t] = 0;
    __syncthreads();
    for (int e = e0r + t; e < e1r; e += 512) atomicAdd(&deg[part[e] & 511], 1);
    __syncthreads();
    const int dg = deg[t];
    const int pdeg = (dg + 7) & ~7;
    sc[t] = pdeg;
    __syncthreads();
    for (int o = 1; o < 512; o <<= 1) {
        int a = (t >= o) ? sc[t - o] : 0;
        __syncthreads();
        sc[t] += a;
        __syncthreads();
    }
    const int excl = (t == 0) ? 0 : sc[t - 1];
    const int pbase = ((e0r + 7) & ~7) + buk * BUKPAD;
    const int start = pbase + excl;
    cur[t] = start;
    if (t < nn) {
        offs[n0 + t] = start;
        nchk[n0 + t] = pdeg >> 2;
        isq[n0 + t]  = rsqrtf((float)(dg + 1));
    }
    for (int j = dg; j < pdeg; ++j) csr[start + j] = -1;   // <=7 pads per node
    __syncthreads();
    for (int e = e0r + t; e < e1r; e += 512) {
        unsigned w = part[e];
        int dl = (int)(w & 511u);
        int p = atomicAdd(&cur[dl], 1);
        csr[p] = (int)(w >> 9);
    }
}

// ---------------- GEMM1 (MFMA): Hs1 = bf16((x @ W1) * isq[row]) ----------------
// also zeroes sentinel row n (block 0).

__global__ __launch_bounds__(256) void k_gemm1(const float* __restrict__ x,
                                               const __bf16* __restrict__ W1t,
                                               const float* __restrict__ isq,
                                               unsigned short* __restrict__ out, int n) {
    if (blockIdx.x == 0 && threadIdx.x < 16) {
        int4 z = {0, 0, 0, 0};
        *(int4*)(out + (size_t)n * 128 + threadIdx.x * 8) = z;
    }
    const int lane = threadIdx.x & 63;
    const int wid  = blockIdx.x * 4 + (threadIdx.x >> 6);
    const int r0 = wid * 16;
    if (r0 >= n) return;
    const int mr = lane & 15;
    const int kg = lane >> 4;

    bf16x8 af[4];
    const float* xrow = x + (size_t)(r0 + mr) * 128 + kg * 8;
    #pragma unroll
    for (int s = 0; s < 4; ++s) {
        f32x4 u0 = *(const f32x4*)(xrow + s * 32);
        f32x4 u1 = *(const f32x4*)(xrow + s * 32 + 4);
        bf16x8 a;
        a[0] = (__bf16)u0[0]; a[1] = (__bf16)u0[1]; a[2] = (__bf16)u0[2]; a[3] = (__bf16)u0[3];
        a[4] = (__bf16)u1[0]; a[5] = (__bf16)u1[1]; a[6] = (__bf16)u1[2]; a[7] = (__bf16)u1[3];
        af[s] = a;
    }
    float sc[4];
    #pragma unroll
    for (int r = 0; r < 4; ++r) sc[r] = isq[r0 + kg * 4 + r];

    #pragma unroll
    for (int nt = 0; nt < 8; ++nt) {
        const __bf16* wp = W1t + (size_t)(nt * 16 + mr) * 128 + kg * 8;
        f32x4 acc = {0.f, 0.f, 0.f, 0.f};
        #pragma unroll
        for (int s = 0; s < 4; ++s) {
            bf16x8 bfr = *(const bf16x8*)(wp + s * 32);
            acc = __builtin_amdgcn_mfma_f32_16x16x32_bf16(af[s], bfr, acc, 0, 0, 0);
        }
        #pragma unroll
        for (int r = 0; r < 4; ++r) {
            int row = r0 + kg * 4 + r;
            out[(size_t)row * 128 + nt * 16 + mr] = f2b(acc[r] * sc[r]);
        }
    }
}

// ------- agg1: wave/node, 16 lanes x 16B per edge row, 4 edges/iter -------
// zero-row sentinel; XCD-swizzled node assignment. AT LINE-RATE ROOFLINE.

__global__ __launch_bounds__(256) void k_agg1(const unsigned short* __restrict__ Hs,
                                              const int* __restrict__ csr,
                                              const int* __restrict__ offs,
                                              const int* __restrict__ nchk,
                                              const float* __restrict__ isq,
                                              const float* __restrict__ b1,
                                              unsigned short* __restrict__ out, int n) {
    const int sb = xcd_swizzle(blockIdx.x, gridDim.x);
    const int wid = sb * 4 + (threadIdx.x >> 6);
    if (wid >= n) return;
    const int lane = threadIdx.x & 63;
    const int g = lane >> 4, p = lane & 15;   // edge slot, 16B piece
    const int d = wid;
    const int e0 = offs[d];
    const int nc = nchk[d];                   // chunks of 4 edges

    float acc[8] = {0.f, 0.f, 0.f, 0.f, 0.f, 0.f, 0.f, 0.f};
    if (g == 0) {  // self loop
        int4 w = *(const int4*)(Hs + (size_t)d * 128 + p * 8);
        acc[0] = b2f_lo((unsigned)w.x); acc[1] = b2f_hi((unsigned)w.x);
        acc[2] = b2f_lo((unsigned)w.y); acc[3] = b2f_hi((unsigned)w.y);
        acc[4] = b2f_lo((unsigned)w.z); acc[5] = b2f_hi((unsigned)w.z);
        acc[6] = b2f_lo((unsigned)w.w); acc[7] = b2f_hi((unsigned)w.w);
    }

    #pragma unroll 4
    for (int c = 0; c < nc; ++c) {
        int cur = csr[e0 + 4 * c + g];
        unsigned srow = min((unsigned)cur, (unsigned)n);   // -1 -> zero row n
        int4 w = *(const int4*)(Hs + (size_t)srow * 128 + p * 8);
        acc[0] += b2f_lo((unsigned)w.x); acc[1] += b2f_hi((unsigned)w.x);
        acc[2] += b2f_lo((unsigned)w.y); acc[3] += b2f_hi((unsigned)w.y);
        acc[4] += b2f_lo((unsigned)w.z); acc[5] += b2f_hi((unsigned)w.z);
        acc[6] += b2f_lo((unsigned)w.w); acc[7] += b2f_hi((unsigned)w.w);
    }
    #pragma unroll
    for (int j = 0; j < 8; ++j) {
        acc[j] += __shfl_xor(acc[j], 16, 64);
        acc[j] += __shfl_xor(acc[j], 32, 64);
    }
    if (g == 0) {
        const float s = isq[d];
        f32x4 bb0 = *(const f32x4*)(b1 + p * 8);
        f32x4 bb1 = *(const f32x4*)(b1 + p * 8 + 4);
        unsigned short o[8];
        o[0] = f2b(fmaxf(fmaf(acc[0], s, bb0[0]), 0.f));
        o[1] = f2b(fmaxf(fmaf(acc[1], s, bb0[1]), 0.f));
        o[2] = f2b(fmaxf(fmaf(acc[2], s, bb0[2]), 0.f));
        o[3] = f2b(fmaxf(fmaf(acc[3], s, bb0[3]), 0.f));
        o[4] = f2b(fmaxf(fmaf(acc[4], s, bb1[0]), 0.f));
        o[5] = f2b(fmaxf(fmaf(acc[5], s, bb1[1]), 0.f));
        o[6] = f2b(fmaxf(fmaf(acc[6], s, bb1[2]), 0.f));
        o[7] = f2b(fmaxf(fmaf(acc[7], s, bb1[3]), 0.f));
        int4 r;
        r.x = (int)((unsigned)o[0] | ((unsigned)o[1] << 16));
        r.y = (int)((unsigned)o[2] | ((unsigned)o[3] << 16));
        r.z = (int)((unsigned)o[4] | ((unsigned)o[5] << 16));
        r.w = (int)((unsigned)o[6] | ((unsigned)o[7] << 16));
        *(int4*)(out + (size_t)d * 128 + p * 8) = r;
    }
}

// ------- GEMM2 (MFMA): Hs2 = bf16((H1 @ W2pad64) * isq[row]), 64-wide out ----
// also zeroes sentinel row n (block 0).

__global__ __launch_bounds__(256) void k_gemm2(const __bf16* __restrict__ h,
                                               const __bf16* __restrict__ W2t,
                                               const float* __restrict__ isq,
                                               unsigned short* __restrict__ out, int n) {
    if (blockIdx.x == 0 && threadIdx.x < 8) {
        int4 z = {0, 0, 0, 0};
        *(int4*)(out + (size_t)n * 64 + threadIdx.x * 8) = z;
    }
    const int lane = threadIdx.x & 63;
    const int wid  = blockIdx.x * 4 + (threadIdx.x >> 6);
    const int r0 = wid * 16;
    if (r0 >= n) return;
    const int mr = lane & 15;
    const int kg = lane >> 4;

    bf16x8 af[4];
    const __bf16* hrow = h + (size_t)(r0 + mr) * 128 + kg * 8;
    #pragma unroll
    for (int s = 0; s < 4; ++s) af[s] = *(const bf16x8*)(hrow + s * 32);
    float sc[4];
    #pragma unroll
    for (int r = 0; r < 4; ++r) sc[r] = isq[r0 + kg * 4 + r];

    #pragma unroll
    for (int nt = 0; nt < 4; ++nt) {
        const __bf16* wp = W2t + (size_t)(nt * 16 + mr) * 128 + kg * 8;
        f32x4 acc = {0.f, 0.f, 0.f, 0.f};
        #pragma unroll
        for (int s = 0; s < 4; ++s) {
            bf16x8 bfr = *(const bf16x8*)(wp + s * 32);
            acc = __builtin_amdgcn_mfma_f32_16x16x32_bf16(af[s], bfr, acc, 0, 0, 0);
        }
        int col = nt * 16 + mr;
        #pragma unroll
        for (int r = 0; r < 4; ++r) {
            int row = r0 + kg * 4 + r;
            out[(size_t)row * 64 + col] = f2b(acc[r] * sc[r]);
        }
    }
}

// ------- agg2: 8 nodes/wave, 8-lane group per node, serial edge loop --------
// Each lane owns 8 ch of its group's node -> NO accumulate reduction; softmax
// epilogue amortized over 8 nodes per wave. csr read is group-uniform.

__global__ __launch_bounds__(256) void k_agg2(const unsigned short* __restrict__ Hs,
                                              const int* __restrict__ csr,
                                              const int* __restrict__ offs,
                                              const int* __restrict__ nchk,
                                              const float* __restrict__ isq,
                                              const float* __restrict__ b2,
                                              float* __restrict__ out, int n) {
    const int sb = xcd_swizzle(blockIdx.x, gridDim.x);
    const int lane = threadIdx.x & 63;
    const int grp = lane >> 3;                 // node sub-index 0..7
    const int q = lane & 7;                    // 16B piece of the 128B row
    const int d = (sb * 4 + (threadIdx.x >> 6)) * 8 + grp;
    if (d >= n) return;
    const int e0 = offs[d];
    const int ne = nchk[d] << 2;               // padded length (x8)

    float acc[8];
    {   // self row — each group its own node, all lanes active, no duplication
        int4 w = *(const int4*)(Hs + (size_t)d * 64 + q * 8);
        acc[0] = b2f_lo((unsigned)w.x); acc[1] = b2f_hi((unsigned)w.x);
        acc[2] = b2f_lo((unsigned)w.y); acc[3] = b2f_hi((unsigned)w.y);
        acc[4] = b2f_lo((unsigned)w.z); acc[5] = b2f_hi((unsigned)w.z);
        acc[6] = b2f_lo((unsigned)w.w); acc[7] = b2f_hi((unsigned)w.w);
    }
    #pragma unroll 2
    for (int e = 0; e < ne; ++e) {
        int cur = csr[e0 + e];                 // group-uniform address
        unsigned srow = min((unsigned)cur, (unsigned)n);   // -1 -> zero row n
        int4 w = *(const int4*)(Hs + (size_t)srow * 64 + q * 8);
        acc[0] += b2f_lo((unsigned)w.x); acc[1] += b2f_hi((unsigned)w.x);
        acc[2] += b2f_lo((unsigned)w.y); acc[3] += b2f_hi((unsigned)w.y);
        acc[4] += b2f_lo((unsigned)w.z); acc[5] += b2f_hi((unsigned)w.z);
        acc[6] += b2f_lo((unsigned)w.w); acc[7] += b2f_hi((unsigned)w.w);
    }

    // softmax over 40 real ch: lanes q=0..4 hold ch q*8..q*8+7
    const float s = isq[d];
    const bool real = q < 5;
    const int qb = real ? q : 4;               // avoid OOB read of b2[40..]
    f32x4 b0 = *(const f32x4*)(b2 + qb * 8);
    f32x4 b1v = *(const f32x4*)(b2 + qb * 8 + 4);
    float v[8];
    v[0] = fmaf(acc[0], s, b0[0]);  v[1] = fmaf(acc[1], s, b0[1]);
    v[2] = fmaf(acc[2], s, b0[2]);  v[3] = fmaf(acc[3], s, b0[3]);
    v[4] = fmaf(acc[4], s, b1v[0]); v[5] = fmaf(acc[5], s, b1v[1]);
    v[6] = fmaf(acc[6], s, b1v[2]); v[7] = fmaf(acc[7], s, b1v[3]);

    float lm = -INFINITY;
    if (real) {
        lm = v[0];
        #pragma unroll
        for (int j = 1; j < 8; ++j) lm = fmaxf(lm, v[j]);
    }
    lm = fmaxf(lm, __shfl_xor(lm, 1, 64));
    lm = fmaxf(lm, __shfl_xor(lm, 2, 64));
    lm = fmaxf(lm, __shfl_xor(lm, 4, 64));
    float es = 0.f;
    if (real) {
        #pragma unroll
        for (int j = 0; j < 8; ++j) es += expf(v[j] - lm);
    }
    es += __shfl_xor(es, 1, 64);
    es += __shfl_xor(es, 2, 64);
    es += __shfl_xor(es, 4, 64);
    const float lse = lm + logf(es);
    if (real) {
        f32x4 r0, r1;
        r0[0] = v[0] - lse; r0[1] = v[1] - lse; r0[2] = v[2] - lse; r0[3] = v[3] - lse;
        r1[0] = v[4] - lse; r1[1] = v[5] - lse; r1[2] = v[6] - lse; r1[3] = v[7] - lse;
        float* op = out + (size_t)d * 40 + q * 8;
        *(f32x4*)op = r0;
        *(f32x4*)(op + 4) = r1;
    }
}

// ---------------- launch ----------------

extern "C" void kernel_launch(void* const* d_in, const int* in_sizes, int n_in,
                              void* d_out, int out_size, void* d_ws, size_t ws_size,
                              hipStream_t stream) {
    const float* x  = (const float*)d_in[0];
    const int*   ei = (const int*)d_in[1];
    const float* W1 = (const float*)d_in[2];
    const float* b1 = (const float*)d_in[3];
    const float* W2 = (const float*)d_in[4];
    const float* b2 = (const float*)d_in[5];
    float* out = (float*)d_out;

    const int N = in_sizes[0] / 128;
    const int E = in_sizes[1] / 2;
    const int* srcA = ei;
    const int* dstA = ei + E;
    const int nbuk = (N + 511) >> 9;              // <= 256
    const int chunk = (E + NB_SC - 1) / NB_SC;
    const int M = nbuk * NB_SC;
    const int csrCap = E + nbuk * BUKPAD + 64;

    char* ws = (char*)d_ws;
    size_t off = 0;
    auto alloc = [&](size_t bytes) -> void* {
        void* p = ws + off;
        off += (bytes + 255) & ~(size_t)255;
        return p;
    };
    int*      hist   = (int*)alloc((size_t)M * 4);
    int*      bukpre = (int*)alloc(260 * 4);
    unsigned* part   = (unsigned*)alloc((size_t)E * 4);
    int*      offs   = (int*)alloc((size_t)N * 4);
    int*      nchk   = (int*)alloc((size_t)N * 4);
    float*    isq    = (float*)alloc((size_t)N * 4);
    int*      csr    = (int*)alloc((size_t)csrCap * 4);
    __bf16*   W1t    = (__bf16*)alloc(128 * 128 * 2);
    __bf16*   W2t    = (__bf16*)alloc(64 * 128 * 2);
    unsigned short* Hs1 = (unsigned short*)alloc((size_t)(N + 8) * 128 * 2);  // +zero row
    unsigned short* H1  = (unsigned short*)alloc((size_t)N * 128 * 2);
    unsigned short* Hs2 = (unsigned short*)alloc((size_t)(N + 8) * 64 * 2);   // +zero row

    k_hist<<<NB_SC, 256, 0, stream>>>(dstA, hist, E, nbuk, chunk, W1, W2, W1t, W2t);
    k_scatter<<<NB_SC, 256, 0, stream>>>(srcA, dstA, hist, bukpre, part, E, nbuk, chunk);
    k_lcsr<<<nbuk, 512, 0, stream>>>(part, bukpre, csr, offs, nchk, isq, E, N, nbuk);

    const int nwav = (N + 15) / 16;
    k_gemm1<<<(nwav + 3) / 4, 256, 0, stream>>>(x, W1t, isq, Hs1, N);
    k_agg1<<<(N + 3) / 4, 256, 0, stream>>>(Hs1, csr, offs, nchk, isq, b1, H1, N);
    k_gemm2<<<(nwav + 3) / 4, 256, 0, stream>>>((const __bf16*)H1, W2t, isq, Hs2, N);
    k_agg2<<<(N + 31) / 32, 256, 0, stream>>>(Hs2, csr, offs, nchk, isq, b2, out, N);
}